// Round 7
// baseline (693.669 us; speedup 1.0000x reference)
//
#include <hip/hip_runtime.h>
#include <cstdint>
#include <cstddef>

#define BB   64
#define TT   512
#define CC   300
#define K1   256    // static max k for layer-1 kmax
#define RS   264    // padded ylds row: [4 zero | 256 data | 4 pad]
#define NG2  75     // fused groups: conv1 groups {2g,2g+1} + conv2 group g

__device__ __forceinline__ unsigned f2key(float f) {
    unsigned u = __float_as_uint(f);
    return (u & 0x80000000u) ? ~u : (u | 0x80000000u);   // monotone float->uint
}
__device__ __forceinline__ float key2f(unsigned k) {
    unsigned u = (k & 0x80000000u) ? (k & 0x7FFFFFFFu) : ~k;
    return __uint_as_float(u);
}
__device__ __forceinline__ float fast_tanh(float x) {
    float e = __expf(2.0f * x);
    return 1.0f - 2.0f * __builtin_amdgcn_rcpf(e + 1.0f);
}
__device__ __forceinline__ int mbcnt64(unsigned long long m) {
    return (int)__builtin_amdgcn_mbcnt_hi((unsigned)(m >> 32),
                 __builtin_amdgcn_mbcnt_lo((unsigned)m, 0u));
}

__global__ void init_out(const float* __restrict__ bfc, float* __restrict__ out) {
    int i = threadIdx.x;
    if (i < 2 * BB) out[i] = (i & 1) ? bfc[0] : 0.0f;
}

// ---------------- conv1 + dynamic k-max (layer 1), row -> LDS ----------------
// (Bit-identical to the R5-verified core: absmax 0.0 in fused context.)
template<int S>
__device__ __forceinline__ void conv1_core(
    const float (* __restrict__ xs)[524], int lane, int n, int k,
    const float* wA, const float* wB, float br, float* __restrict__ row)
{
    constexpr int NV = (S == 8) ? 16 : 12;
    const int t0 = S * lane;

    float xa[NV], xb[NV];
    #pragma unroll
    for (int q = 0; q < NV / 4; ++q) {
        *(float4*)&xa[4 * q] = *(const float4*)&xs[0][t0 + 4 * q];
        *(float4*)&xb[4 * q] = *(const float4*)&xs[1][t0 + 4 * q];
    }

    float v[S + 1];
    #pragma unroll
    for (int j = 0; j < S; ++j) {
        float acc = br;
        #pragma unroll
        for (int kk = 0; kk < 7; ++kk)
            acc = fmaf(xa[j + kk], wA[kk], fmaf(xb[j + kk], wB[kk], acc));
        v[j] = (t0 + j < n) ? acc : -INFINITY;
    }
    v[S] = -INFINITY;
    if (S == 8 && n > 512) {                 // tail t = 512..517, lanes 0..5
        if (lane < 6 && 512 + lane < n) {
            float acc = br;
            #pragma unroll
            for (int kk = 0; kk < 7; ++kk)
                acc = fmaf(xs[0][512 + lane + kk], wA[kk],
                      fmaf(xs[1][512 + lane + kk], wB[kk], acc));
            v[S] = acc;
        }
    }

    float lmax = -INFINITY, lmin = INFINITY;
    #pragma unroll
    for (int j = 0; j <= S; ++j) {
        lmax = fmaxf(lmax, v[j]);
        lmin = fminf(lmin, (v[j] == -INFINITY) ? INFINITY : v[j]);
    }
    #pragma unroll
    for (int o = 32; o; o >>= 1) {
        lmax = fmaxf(lmax, __shfl_xor(lmax, o));
        lmin = fminf(lmin, __shfl_xor(lmin, o));
    }
    const float vmax = lmax, vmin = lmin;

    float tau; bool found = false;
    int cmax = 0;
    #pragma unroll
    for (int j = 0; j <= S; ++j) cmax += (int)__popcll(__ballot(v[j] == vmax));
    if (cmax >= k) {
        tau = vmax;
    } else {
        float lo = vmin, hi = vmax;          // inv: cnt(>=lo)>k, cnt(>=hi)<k
        tau = lo;
        while (true) {
            float mid = 0.5f * (lo + hi);
            if (mid == lo || mid == hi) { tau = lo; break; }
            int c = 0;
            #pragma unroll
            for (int j = 0; j <= S; ++j)
                c += (int)__popcll(__ballot(v[j] >= mid));
            if (c == k) { tau = mid; found = true; break; }
            if (c > k) lo = mid; else hi = mid;
        }
    }

    bool bG[S + 1], bE[S + 1];
    unsigned long long mG[S + 1], mE[S + 1];
    #pragma unroll
    for (int j = 0; j <= S; ++j) {
        bG[j] = found ? (v[j] >= tau) : (v[j] > tau);
        bE[j] = found ? false : (v[j] == tau);
        mG[j] = __ballot(bG[j]);
        mE[j] = __ballot(bE[j]);
    }
    int cg = 0;
    #pragma unroll
    for (int j = 0; j <= S; ++j) cg += (int)__popcll(mG[j]);
    const int budget = k - cg;

    int SGm = 0, SEm = 0, FGm = 0, FEm = 0;
    #pragma unroll
    for (int j = 0; j < S; ++j) {
        SGm += mbcnt64(mG[j]);  FGm += (int)__popcll(mG[j]);
        SEm += mbcnt64(mE[j]);  FEm += (int)__popcll(mE[j]);
    }
    int ownG = 0, ownE = 0;
    #pragma unroll
    for (int j = 0; j < S; ++j) {            // lane owns t = S*lane + j
        if (bG[j] || bE[j]) {
            int E = SEm + ownE;
            if (bG[j] || E < budget) {
                int pos = SGm + ownG + min(E, budget);
                row[4 + pos] = fast_tanh(v[j]);
            }
        }
        ownG += bG[j] ? 1 : 0;  ownE += bE[j] ? 1 : 0;
    }
    if (S == 8 && (bG[S] || bE[S])) {        // tail t >= 512 > all main t
        int E = FEm + mbcnt64(mE[S]);
        if (bG[S] || E < budget) {
            int pos = FGm + mbcnt64(mG[S]) + min(E, budget);
            row[4 + pos] = fast_tanh(v[S]);
        }
    }
    // zeros: head [0,4); tail [4+k, 4+k+8)∩[0,RS) — conv2 reads <= 4 past k.
    if (lane < 4) row[lane] = 0.0f;
    if (lane < 8) { int idx = 4 + k + lane; if (idx < RS) row[idx] = 0.0f; }
}

// ---------------- fused: conv1 -> kmax -> tanh -> conv2 -> kmax4 -> tanh -> fc ----------------
// One block per (g2, b); 12 waves, one conv1 channel per wave (spill fix vs R5).
__global__ __launch_bounds__(768, 6) void fused_dcnn(
    const float* __restrict__ x, const int* __restrict__ lengths,
    const float* __restrict__ w1, const float* __restrict__ b1,
    const float* __restrict__ w2, const float* __restrict__ b2,
    const float* __restrict__ wfc, float* __restrict__ out)
{
    const int g   = blockIdx.x;              // conv2 group, 0..74
    const int b   = blockIdx.y;
    const int tid = threadIdx.x;
    const int r   = tid >> 6, lane = tid & 63;
    const int ru  = __builtin_amdgcn_readfirstlane(r);   // wave-uniform in SGPR
    const int len = lengths[b];
    const int n   = len + 6;
    const int k   = max(4, (len + 1) >> 1);
    const int n2  = k + 4;

    __shared__ __align__(16) float xs[4][524];     // input channels 4g..4g+3
    __shared__ __align__(16) float ylds[12][264];  // layer-1 output rows
    __shared__ float partial[12];

    // stage x: one float4 per position (channels 4g..4g+3 contiguous, 16B aligned)
    for (int q = tid; q < 524; q += 768) {
        int t = q - 6;
        float4 xv = make_float4(0.f, 0.f, 0.f, 0.f);
        if (t >= 0 && t < len)
            xv = *(const float4*)&x[((size_t)b * TT + t) * CC + 4 * g];
        xs[0][q] = xv.x; xs[1][q] = xv.y; xs[2][q] = xv.z; xs[3][q] = xv.w;
    }
    __syncthreads();

    // ---- phase 1: wave r -> conv1 channel (2g + r/6)*6 + r%6 ----
    {
        const int grp = ru / 6, rr = ru - 6 * grp;
        const float* wp = w1 + ((size_t)(2 * g + grp) * 6 + rr) * 14;  // scalar loads
        float wA[7], wB[7];
        #pragma unroll
        for (int i = 0; i < 7; ++i) { wA[i] = wp[i]; wB[i] = wp[7 + i]; }
        const float br = b1[(size_t)(2 * g + grp) * 6 + rr];
        float* row = &ylds[ru][0];
        if (n <= 256) conv1_core<4>(&xs[2 * grp], lane, n, k, wA, wB, br, row);
        else          conv1_core<8>(&xs[2 * grp], lane, n, k, wA, wB, br, row);
    }
    __syncthreads();

    // ---- phase 2: wave r -> conv2 channels {r} (+ {r+12} if r<2) ----
    const int nch = (ru < 2) ? 2 : 1;
    const float* __restrict__ wg = w2 + (size_t)g * 840;

    float bias_s[2];
    #pragma unroll
    for (int it = 0; it < 2; ++it)
        bias_s[it] = (it < nch) ? b2[(size_t)g * 14 + (ru + 12 * it)] : 0.0f;

    float acc[2][4];
    #pragma unroll
    for (int it = 0; it < 2; ++it)
        #pragma unroll
        for (int j = 0; j < 4; ++j) acc[it][j] = bias_s[it];

    for (int c = 0; c < 12; ++c) {
        const float4 f0 = *(const float4*)&ylds[c][4 * lane];
        const float4 f1 = *(const float4*)&ylds[c][4 * lane + 4];
        const float e[8] = {f0.x, f0.y, f0.z, f0.w, f1.x, f1.y, f1.z, f1.w};
        #pragma unroll
        for (int it = 0; it < 2; ++it) {
            if (it < nch) {
                const float* wp = wg + (ru + 12 * it) * 60 + c * 5;    // scalar loads
                #pragma unroll
                for (int kw = 0; kw < 5; ++kw) {
                    const float q = wp[kw];
                    acc[it][0] = fmaf(e[0 + kw], q, acc[it][0]);
                    acc[it][1] = fmaf(e[1 + kw], q, acc[it][1]);
                    acc[it][2] = fmaf(e[2 + kw], q, acc[it][2]);
                    acc[it][3] = fmaf(e[3 + kw], q, acc[it][3]);
                }
            }
        }
    }

    float tval[2];
    #pragma unroll
    for (int it = 0; it < 2; ++it) tval[it] = -INFINITY;
    if (n2 > 256) {                          // tail positions 256..259 (k >= 253)
        if (lane < 4 && 256 + lane < n2) {
            const int w = 256 + lane;
            float ta[2];
            #pragma unroll
            for (int it = 0; it < 2; ++it) ta[it] = bias_s[it];
            for (int c = 0; c < 12; ++c) {
                #pragma unroll
                for (int kw = 0; kw < 5; ++kw) {
                    const float xv = ylds[c][w + kw];
                    #pragma unroll
                    for (int it = 0; it < 2; ++it)
                        if (it < nch)
                            ta[it] = fmaf(xv, wg[(ru + 12 * it) * 60 + c * 5 + kw], ta[it]);
                }
            }
            #pragma unroll
            for (int it = 0; it < 2; ++it) tval[it] = ta[it];
        }
    }

    float fcsum = 0.0f;
    #pragma unroll
    for (int it = 0; it < 2; ++it) {
        if (it < nch) {
            const int r2 = ru + 12 * it;     // wave-uniform
            unsigned kk[5];
            #pragma unroll
            for (int j = 0; j < 4; ++j)
                kk[j] = (4 * lane + j < n2) ? f2key(acc[it][j]) : 0u;
            kk[4] = (tval[it] != -INFINITY) ? f2key(tval[it]) : 0u;

            float tv[4]; int ti[4];
            #pragma unroll
            for (int round = 0; round < 4; ++round) {
                unsigned best = max(max(kk[0], kk[1]), max(kk[2], kk[3]));
                best = max(best, kk[4]);
                #pragma unroll
                for (int o = 32; o; o >>= 1)
                    best = max(best, (unsigned)__shfl_xor((int)best, o));
                int jm = 5;
                #pragma unroll
                for (int j = 4; j >= 0; --j) if (kk[j] == best) jm = j;
                unsigned long long m = __ballot(jm < 5);
                int wl;
                if (__popcll(m) == 1) {
                    wl = __ffsll((long long)m) - 1;
                } else {                     // exact value tie: smallest t wins
                    int myt = (jm == 4) ? (256 + lane)
                            : (jm < 4 ? 4 * lane + jm : 0x7FFFFFFF);
                    int tmin = myt;
                    #pragma unroll
                    for (int o = 32; o; o >>= 1) tmin = min(tmin, __shfl_xor(tmin, o));
                    wl = __ffsll((long long)__ballot(myt == tmin)) - 1;
                }
                const int jw = __shfl(jm, wl);
                ti[round] = (jw == 4) ? (256 + wl) : (4 * wl + jw);
                tv[round] = key2f(best);
                #pragma unroll
                for (int j = 0; j < 5; ++j)
                    if (lane == wl && jm == j) kk[j] = 0u;
            }
            #define CSW(a,bq) if (ti[a] > ti[bq]) { int t_=ti[a]; ti[a]=ti[bq]; ti[bq]=t_; float f_=tv[a]; tv[a]=tv[bq]; tv[bq]=f_; }
            CSW(0,1) CSW(2,3) CSW(0,2) CSW(1,3) CSW(1,2)
            #undef CSW

            const float* wfp = wfc + r2 * 75 + g;                  // scalar loads
            float s = fast_tanh(tv[0]) * wfp[0];
            s = fmaf(fast_tanh(tv[1]), wfp[1050], s);
            s = fmaf(fast_tanh(tv[2]), wfp[2100], s);
            s = fmaf(fast_tanh(tv[3]), wfp[3150], s);
            fcsum += s;
        }
    }
    if (lane == 0) partial[ru] = fcsum;
    __syncthreads();
    if (tid == 0) {
        float s = partial[0];
        #pragma unroll
        for (int i = 1; i < 12; ++i) s += partial[i];
        atomicAdd(&out[b * 2 + 1], s);
    }
}

extern "C" void kernel_launch(void* const* d_in, const int* in_sizes, int n_in,
                              void* d_out, int out_size, void* d_ws, size_t ws_size,
                              hipStream_t stream) {
    const float* x       = (const float*)d_in[0];
    const int*   lengths = (const int*)  d_in[1];
    const float* w1      = (const float*)d_in[2];
    const float* b1      = (const float*)d_in[3];
    const float* w2      = (const float*)d_in[4];
    const float* b2      = (const float*)d_in[5];
    const float* wfc     = (const float*)d_in[6];
    const float* bfc     = (const float*)d_in[7];
    float* out = (float*)d_out;

    init_out<<<dim3(1), dim3(128), 0, stream>>>(bfc, out);
    fused_dcnn<<<dim3(NG2, BB), dim3(768), 0, stream>>>(x, lengths, w1, b1, w2, b2, wfc, out);
}

// Round 9
// 331.552 us; speedup vs baseline: 2.0922x; 2.0922x over previous
//
#include <hip/hip_runtime.h>
#include <cstdint>
#include <cstddef>

#define BB   64
#define TT   512
#define CC   300
#define K1   256    // static max k for layer-1 kmax
#define RS   264    // padded ylds row: [4 zero | 256 data | 4 pad]
#define NG2  75     // fused groups: conv1 groups {2g,2g+1} + conv2 group g

__device__ __forceinline__ unsigned f2key(float f) {
    unsigned u = __float_as_uint(f);
    return (u & 0x80000000u) ? ~u : (u | 0x80000000u);   // monotone float->uint
}
__device__ __forceinline__ float key2f(unsigned k) {
    unsigned u = (k & 0x80000000u) ? (k & 0x7FFFFFFFu) : ~k;
    return __uint_as_float(u);
}
__device__ __forceinline__ float fast_tanh(float x) {
    float e = __expf(2.0f * x);
    return 1.0f - 2.0f * __builtin_amdgcn_rcpf(e + 1.0f);
}
__device__ __forceinline__ int mbcnt64(unsigned long long m) {
    return (int)__builtin_amdgcn_mbcnt_hi((unsigned)(m >> 32),
                 __builtin_amdgcn_mbcnt_lo((unsigned)m, 0u));
}

__global__ void init_out(const float* __restrict__ bfc, float* __restrict__ out) {
    int i = threadIdx.x;
    if (i < 2 * BB) out[i] = (i & 1) ? bfc[0] : 0.0f;
}

// ---------------- conv1 + dynamic k-max (layer 1), row -> LDS ----------------
// Low-register rewrite of the R4/R5-verified core (identical selection math):
//  - input channels processed sequentially through ONE reused window array
//  - ballot masks never stored: pass 1 accumulates scalar cross-lane counts
//    (SGm/SEm = greater/equal in lanes-below across all main slots; FGm/FEm =
//    totals), pass 2 uses only own-lane booleans + running ownG/ownE.
// Position of a kept slot t = S*lane+j: #greater-before-t + min(#equal-before-t, budget),
// where cross-lane terms are SGm/SEm (lane'<lane, any j') and own-lane terms ownG/ownE.
template<int S>
__device__ __forceinline__ void conv1_core(
    const float (* __restrict__ xs)[524], int lane, int n, int k,
    const float* wA, const float* wB, float br, float* __restrict__ row)
{
    constexpr int NV = (S == 8) ? 16 : 12;
    const int t0 = S * lane;

    float v[S + 1];
    {
        float xr[NV];                        // reused for both input channels
        #pragma unroll
        for (int q = 0; q < NV / 4; ++q)
            *(float4*)&xr[4 * q] = *(const float4*)&xs[0][t0 + 4 * q];
        #pragma unroll
        for (int j = 0; j < S; ++j) {
            float acc = br;
            #pragma unroll
            for (int kk = 0; kk < 7; ++kk) acc = fmaf(xr[j + kk], wA[kk], acc);
            v[j] = acc;
        }
        #pragma unroll
        for (int q = 0; q < NV / 4; ++q)
            *(float4*)&xr[4 * q] = *(const float4*)&xs[1][t0 + 4 * q];
        #pragma unroll
        for (int j = 0; j < S; ++j) {
            float acc = v[j];
            #pragma unroll
            for (int kk = 0; kk < 7; ++kk) acc = fmaf(xr[j + kk], wB[kk], acc);
            v[j] = (t0 + j < n) ? acc : -INFINITY;
        }
    }
    v[S] = -INFINITY;
    if (S == 8 && n > 512) {                 // tail t = 512..517, lanes 0..5
        if (lane < 6 && 512 + lane < n) {
            float acc = br;
            #pragma unroll
            for (int kk = 0; kk < 7; ++kk)
                acc = fmaf(xs[0][512 + lane + kk], wA[kk],
                      fmaf(xs[1][512 + lane + kk], wB[kk], acc));
            v[S] = acc;
        }
    }

    float lmax = -INFINITY, lmin = INFINITY;
    #pragma unroll
    for (int j = 0; j <= S; ++j) {
        lmax = fmaxf(lmax, v[j]);
        lmin = fminf(lmin, (v[j] == -INFINITY) ? INFINITY : v[j]);
    }
    #pragma unroll
    for (int o = 32; o; o >>= 1) {
        lmax = fmaxf(lmax, __shfl_xor(lmax, o));
        lmin = fminf(lmin, __shfl_xor(lmin, o));
    }
    const float vmax = lmax, vmin = lmin;

    float tau; bool found = false;
    int cmax = 0;
    #pragma unroll
    for (int j = 0; j <= S; ++j) cmax += (int)__popcll(__ballot(v[j] == vmax));
    if (cmax >= k) {
        tau = vmax;
    } else {
        float lo = vmin, hi = vmax;          // inv: cnt(>=lo)>k, cnt(>=hi)<k
        tau = lo;
        while (true) {
            float mid = 0.5f * (lo + hi);
            if (mid == lo || mid == hi) { tau = lo; break; }
            int c = 0;
            #pragma unroll
            for (int j = 0; j <= S; ++j)
                c += (int)__popcll(__ballot(v[j] >= mid));
            if (c == k) { tau = mid; found = true; break; }
            if (c > k) lo = mid; else hi = mid;
        }
    }

    // pass 1: cross-lane count scalars (no stored masks; only tail masks kept)
    int SGm = 0, SEm = 0, FGm = 0, FEm = 0;
    #pragma unroll
    for (int j = 0; j < S; ++j) {
        bool isG = found ? (v[j] >= tau) : (v[j] > tau);
        bool isE = !found && (v[j] == tau);
        unsigned long long mG = __ballot(isG);
        unsigned long long mE = __ballot(isE);
        SGm += mbcnt64(mG);  FGm += (int)__popcll(mG);
        SEm += mbcnt64(mE);  FEm += (int)__popcll(mE);
    }
    const bool tG = found ? (v[S] >= tau) : (v[S] > tau);
    const bool tE = !found && (v[S] == tau);
    const unsigned long long mGS = __ballot(tG);
    const unsigned long long mES = __ballot(tE);
    const int budget = k - (FGm + (int)__popcll(mGS));

    // pass 2: emission — own-lane booleans only
    int ownG = 0, ownE = 0;
    #pragma unroll
    for (int j = 0; j < S; ++j) {            // lane owns t = S*lane + j
        bool isG = found ? (v[j] >= tau) : (v[j] > tau);
        bool isE = !found && (v[j] == tau);
        if (isG || isE) {
            int E = SEm + ownE;
            if (isG || E < budget) {
                int pos = SGm + ownG + min(E, budget);
                row[4 + pos] = fast_tanh(v[j]);
            }
        }
        ownG += isG ? 1 : 0;  ownE += isE ? 1 : 0;
    }
    if (S == 8 && (tG || tE)) {              // tail t >= 512 > all main t
        int E = FEm + mbcnt64(mES);
        if (tG || E < budget) {
            int pos = FGm + mbcnt64(mGS) + min(E, budget);
            row[4 + pos] = fast_tanh(v[S]);
        }
    }
    // zeros: head [0,4); tail [4+k, 4+k+8)∩[0,RS) — conv2 reads <= 4 past k.
    if (lane < 4) row[lane] = 0.0f;
    if (lane < 8) { int idx = 4 + k + lane; if (idx < RS) row[idx] = 0.0f; }
}

// ---------------- fused: conv1 -> kmax -> tanh -> conv2 -> kmax4 -> tanh -> fc ----------------
// One block per (g2, b); 12 waves, one conv1 channel per wave.
__global__ __launch_bounds__(768, 4) void fused_dcnn(
    const float* __restrict__ x, const int* __restrict__ lengths,
    const float* __restrict__ w1, const float* __restrict__ b1,
    const float* __restrict__ w2, const float* __restrict__ b2,
    const float* __restrict__ wfc, float* __restrict__ out)
{
    const int g   = blockIdx.x;              // conv2 group, 0..74
    const int b   = blockIdx.y;
    const int tid = threadIdx.x;
    const int r   = tid >> 6, lane = tid & 63;
    const int ru  = __builtin_amdgcn_readfirstlane(r);   // wave-uniform in SGPR
    const int len = lengths[b];
    const int n   = len + 6;
    const int k   = max(4, (len + 1) >> 1);
    const int n2  = k + 4;

    __shared__ __align__(16) float xs[4][524];     // input channels 4g..4g+3
    __shared__ __align__(16) float ylds[12][264];  // layer-1 output rows
    __shared__ float partial[12];

    // stage x: one float4 per position (channels 4g..4g+3 contiguous, 16B aligned)
    for (int q = tid; q < 524; q += 768) {
        int t = q - 6;
        float4 xv = make_float4(0.f, 0.f, 0.f, 0.f);
        if (t >= 0 && t < len)
            xv = *(const float4*)&x[((size_t)b * TT + t) * CC + 4 * g];
        xs[0][q] = xv.x; xs[1][q] = xv.y; xs[2][q] = xv.z; xs[3][q] = xv.w;
    }
    __syncthreads();

    // ---- phase 1: wave r -> conv1 channel (2g + r/6)*6 + r%6 ----
    {
        const int grp = ru / 6, rr = ru - 6 * grp;
        const float* wp = w1 + ((size_t)(2 * g + grp) * 6 + rr) * 14;  // scalar loads
        float wA[7], wB[7];
        #pragma unroll
        for (int i = 0; i < 7; ++i) { wA[i] = wp[i]; wB[i] = wp[7 + i]; }
        const float br = b1[(size_t)(2 * g + grp) * 6 + rr];
        float* row = &ylds[ru][0];
        if (n <= 256) conv1_core<4>(&xs[2 * grp], lane, n, k, wA, wB, br, row);
        else          conv1_core<8>(&xs[2 * grp], lane, n, k, wA, wB, br, row);
    }
    __syncthreads();

    // ---- phase 2: wave r -> conv2 channels {r} (+ {r+12} if r<2) ----
    const int nch = (ru < 2) ? 2 : 1;
    const float* __restrict__ wg = w2 + (size_t)g * 840;

    float bias_s[2];
    #pragma unroll
    for (int it = 0; it < 2; ++it)
        bias_s[it] = (it < nch) ? b2[(size_t)g * 14 + (ru + 12 * it)] : 0.0f;

    float acc[2][4];
    #pragma unroll
    for (int it = 0; it < 2; ++it)
        #pragma unroll
        for (int j = 0; j < 4; ++j) acc[it][j] = bias_s[it];

    for (int c = 0; c < 12; ++c) {
        const float4 f0 = *(const float4*)&ylds[c][4 * lane];
        const float4 f1 = *(const float4*)&ylds[c][4 * lane + 4];
        const float e[8] = {f0.x, f0.y, f0.z, f0.w, f1.x, f1.y, f1.z, f1.w};
        #pragma unroll
        for (int it = 0; it < 2; ++it) {
            if (it < nch) {
                const float* wp = wg + (ru + 12 * it) * 60 + c * 5;    // scalar loads
                #pragma unroll
                for (int kw = 0; kw < 5; ++kw) {
                    const float q = wp[kw];
                    acc[it][0] = fmaf(e[0 + kw], q, acc[it][0]);
                    acc[it][1] = fmaf(e[1 + kw], q, acc[it][1]);
                    acc[it][2] = fmaf(e[2 + kw], q, acc[it][2]);
                    acc[it][3] = fmaf(e[3 + kw], q, acc[it][3]);
                }
            }
        }
    }

    float tval[2];
    #pragma unroll
    for (int it = 0; it < 2; ++it) tval[it] = -INFINITY;
    if (n2 > 256) {                          // tail positions 256..259 (k >= 253)
        if (lane < 4 && 256 + lane < n2) {
            const int w = 256 + lane;
            float ta[2];
            #pragma unroll
            for (int it = 0; it < 2; ++it) ta[it] = bias_s[it];
            for (int c = 0; c < 12; ++c) {
                #pragma unroll
                for (int kw = 0; kw < 5; ++kw) {
                    const float xv = ylds[c][w + kw];
                    #pragma unroll
                    for (int it = 0; it < 2; ++it)
                        if (it < nch)
                            ta[it] = fmaf(xv, wg[(ru + 12 * it) * 60 + c * 5 + kw], ta[it]);
                }
            }
            #pragma unroll
            for (int it = 0; it < 2; ++it) tval[it] = ta[it];
        }
    }

    float fcsum = 0.0f;
    #pragma unroll
    for (int it = 0; it < 2; ++it) {
        if (it < nch) {
            const int r2 = ru + 12 * it;     // wave-uniform
            unsigned kk[5];
            #pragma unroll
            for (int j = 0; j < 4; ++j)
                kk[j] = (4 * lane + j < n2) ? f2key(acc[it][j]) : 0u;
            kk[4] = (tval[it] != -INFINITY) ? f2key(tval[it]) : 0u;

            float tv[4]; int ti[4];
            #pragma unroll
            for (int round = 0; round < 4; ++round) {
                unsigned best = max(max(kk[0], kk[1]), max(kk[2], kk[3]));
                best = max(best, kk[4]);
                #pragma unroll
                for (int o = 32; o; o >>= 1)
                    best = max(best, (unsigned)__shfl_xor((int)best, o));
                int jm = 5;
                #pragma unroll
                for (int j = 4; j >= 0; --j) if (kk[j] == best) jm = j;
                unsigned long long m = __ballot(jm < 5);
                int wl;
                if (__popcll(m) == 1) {
                    wl = __ffsll((long long)m) - 1;
                } else {                     // exact value tie: smallest t wins
                    int myt = (jm == 4) ? (256 + lane)
                            : (jm < 4 ? 4 * lane + jm : 0x7FFFFFFF);
                    int tmin = myt;
                    #pragma unroll
                    for (int o = 32; o; o >>= 1) tmin = min(tmin, __shfl_xor(tmin, o));
                    wl = __ffsll((long long)__ballot(myt == tmin)) - 1;
                }
                const int jw = __shfl(jm, wl);
                ti[round] = (jw == 4) ? (256 + wl) : (4 * wl + jw);
                tv[round] = key2f(best);
                #pragma unroll
                for (int j = 0; j < 5; ++j)
                    if (lane == wl && jm == j) kk[j] = 0u;
            }
            #define CSW(a,bq) if (ti[a] > ti[bq]) { int t_=ti[a]; ti[a]=ti[bq]; ti[bq]=t_; float f_=tv[a]; tv[a]=tv[bq]; tv[bq]=f_; }
            CSW(0,1) CSW(2,3) CSW(0,2) CSW(1,3) CSW(1,2)
            #undef CSW

            const float* wfp = wfc + r2 * 75 + g;                  // scalar loads
            float s = fast_tanh(tv[0]) * wfp[0];
            s = fmaf(fast_tanh(tv[1]), wfp[1050], s);
            s = fmaf(fast_tanh(tv[2]), wfp[2100], s);
            s = fmaf(fast_tanh(tv[3]), wfp[3150], s);
            fcsum += s;
        }
    }
    if (lane == 0) partial[ru] = fcsum;
    __syncthreads();
    if (tid == 0) {
        float s = partial[0];
        #pragma unroll
        for (int i = 1; i < 12; ++i) s += partial[i];
        atomicAdd(&out[b * 2 + 1], s);
    }
}

extern "C" void kernel_launch(void* const* d_in, const int* in_sizes, int n_in,
                              void* d_out, int out_size, void* d_ws, size_t ws_size,
                              hipStream_t stream) {
    const float* x       = (const float*)d_in[0];
    const int*   lengths = (const int*)  d_in[1];
    const float* w1      = (const float*)d_in[2];
    const float* b1      = (const float*)d_in[3];
    const float* w2      = (const float*)d_in[4];
    const float* b2      = (const float*)d_in[5];
    const float* wfc     = (const float*)d_in[6];
    const float* bfc     = (const float*)d_in[7];
    float* out = (float*)d_out;

    init_out<<<dim3(1), dim3(128), 0, stream>>>(bfc, out);
    fused_dcnn<<<dim3(NG2, BB), dim3(768), 0, stream>>>(x, lengths, w1, b1, w2, b2, wfc, out);
}